// Round 4
// baseline (107.643 us; speedup 1.0000x reference)
//
#include <hip/hip_runtime.h>
#include <hip/hip_bf16.h>

// CustomBernsteinLayer: out[b,o] = sum_{i,k} ber[b,i,k] * (coeffs[o,i,k]*weights[o,i])
// ber = (1+t)^k (1-t)^(8-k), t = tanh(x).  With e = exp2(2x*log2e):
//   (1-t) = 2/(e+1) = q, (1+t) = q*e, ratio r = e, p0 = q^8, ber_{k+1} = ber_k * r.
// bf16 MFMA GEMM M=16384 N=256 K=2304.
// Round 4: barrier-free per-lane A-gen (validated R3), but
//  - VGPR diet: no x-prefetch array, transient A-frag pack (~190 regs, no spill
//    under the 256 cap from __launch_bounds__(512,2))
//  - 512-thread blocks (8 waves: 2 row-halves x 4 col-slices), grid 256 =
//    1 block/CU: waves w and w+4 read identical B fragments -> L1 sharing,
//    and total B re-read traffic halves vs R3 (580 -> 290 MB).

#define BDIM 16384
#define IDIM 256
#define ODIM 256
#define NK 9
#define NCHUNK 4
#define NSTEP 36
#define STEP_ELEMS (ODIM * 64)   // 16384 bf16 (32 KB) per K-step block

typedef short short8 __attribute__((ext_vector_type(8)));
typedef float floatx4 __attribute__((ext_vector_type(4)));

// ---------------------------------------------------------------------------
// prep (validated): wc[step][e] = bf16(coeffs[o,i,k]*weights[o,i]),
// e = (((o>>4)*2 + s)*64 + (o&15) + quad*16)*8 + j, il = s*32+quad*8+j,
// step = (i>>6)*9 + k. One coalesced 16B store per thread.
// ---------------------------------------------------------------------------
__global__ __launch_bounds__(256) void prep_wc2(const float* __restrict__ weights,
                                                const float* __restrict__ coeffs,
                                                ushort* __restrict__ wc) {
    int idx  = blockIdx.x * 256 + threadIdx.x;  // 73728 chunks
    int step = idx >> 11;
    int c    = idx & 2047;
    int big    = c >> 6;
    int lane_w = c & 63;
    int o    = (big >> 1) * 16 + (lane_w & 15);
    int s    = big & 1;
    int quad = lane_w >> 4;
    int ic = step / 9;
    int k  = step - ic * 9;
    int i0 = ic * 64 + s * 32 + quad * 8;

    const float* cp = coeffs + (size_t)(o * IDIM + i0) * NK + k;
    float4 w0 = *(const float4*)(weights + o * IDIM + i0);
    float4 w1 = *(const float4*)(weights + o * IDIM + i0 + 4);
    float wv[8] = {w0.x, w0.y, w0.z, w0.w, w1.x, w1.y, w1.z, w1.w};

    union { ushort us[8]; int4 v; __hip_bfloat162 h2[4]; } pk;
#pragma unroll
    for (int j = 0; j < 8; j += 2) {
        float a = cp[(size_t)j * NK] * wv[j];
        float b = cp[(size_t)(j + 1) * NK] * wv[j + 1];
        pk.h2[j >> 1] = __float22bfloat162_rn(make_float2(a, b));
    }
    *(int4*)(wc + (size_t)step * STEP_ELEMS + (size_t)c * 8) = pk.v;
}

// ---------------------------------------------------------------------------
// GEMM: 256 blocks x 512 threads (8 waves). Block rows row0=blk*64; wave w:
// half = w>>2 (rows row0+half*32..+31), wv4 = w&3 (cols wv4*64..+63).
// Per-lane basis state for its own A-fragment slots:
//   rows rb + m*16 + (lane&15), m in {0,1}; i_local = s*32 + (lane>>4)*8 + j.
// B fragments double-buffered in registers from global (L1/L2-resident wc).
// No LDS, no barriers.
// ---------------------------------------------------------------------------
__global__ __launch_bounds__(512, 2) void bern_gemm(const float* __restrict__ x,
                                                    const ushort* __restrict__ wc,
                                                    float* __restrict__ out) {
    const int tid  = threadIdx.x;
    const int wave = tid >> 6;
    const int lane = tid & 63;
    const int half = wave >> 2;
    const int wv4  = wave & 3;
    const int rb   = blockIdx.x * 64 + half * 32;
    const int lrow = lane & 15;
    const int jseg = (lane >> 4) * 8;      // 0,8,16,24

    float p[2][2][8];   // [m][s][j]: x at chunk boundary, then running ber value
    float r[2][2][8];   // ratio e = exp2(2x log2 e)
    floatx4 acc[2][4];
    floatx4 zero = {0.0f, 0.0f, 0.0f, 0.0f};
#pragma unroll
    for (int m = 0; m < 2; ++m)
#pragma unroll
        for (int n = 0; n < 4; ++n)
            acc[m][n] = zero;

    // load x for chunk ic into p[][][] (raw x values)
#define LOAD_X(ic_)                                                             \
    {                                                                           \
        _Pragma("unroll") for (int m = 0; m < 2; ++m)                           \
        _Pragma("unroll") for (int s = 0; s < 2; ++s) {                         \
            const float* xp = x + (size_t)(rb + m * 16 + lrow) * IDIM           \
                              + (ic_) * 64 + s * 32 + jseg;                     \
            float4 v0 = *(const float4*)(xp);                                   \
            float4 v1 = *(const float4*)(xp + 4);                               \
            p[m][s][0] = v0.x; p[m][s][1] = v0.y;                               \
            p[m][s][2] = v0.z; p[m][s][3] = v0.w;                               \
            p[m][s][4] = v1.x; p[m][s][5] = v1.y;                               \
            p[m][s][6] = v1.z; p[m][s][7] = v1.w;                               \
        }                                                                       \
    }

    // transform raw x in p -> (p = (1-t)^8, r = e)
#define SETUP_BASIS()                                                           \
    {                                                                           \
        _Pragma("unroll") for (int m = 0; m < 2; ++m)                           \
        _Pragma("unroll") for (int s = 0; s < 2; ++s)                           \
        _Pragma("unroll") for (int e = 0; e < 8; ++e) {                         \
            float t  = __builtin_amdgcn_exp2f(p[m][s][e] * 2.8853900817779268f);\
            float q  = 2.0f * __builtin_amdgcn_rcpf(t + 1.0f);                  \
            float q2 = q * q;                                                   \
            float q4 = q2 * q2;                                                 \
            p[m][s][e] = q4 * q4;                                               \
            r[m][s][e] = t;                                                     \
        }                                                                       \
    }

    LOAD_X(0);
    SETUP_BASIS();

    // ---- B register double-buffer; preload step 0 ----
    short8 bfr[2][2][4];   // [buf][s][n]
#pragma unroll
    for (int s = 0; s < 2; ++s)
#pragma unroll
        for (int n = 0; n < 4; ++n)
            bfr[0][s][n] = *(const short8*)(wc + (((wv4 * 4 + n) * 2 + s) * 64 + lane) * 8);

#pragma unroll
    for (int ic = 0; ic < NCHUNK; ++ic) {
#pragma unroll
        for (int k = 0; k < NK; ++k) {
            const int step = ic * NK + k;
            const int cur  = step & 1;
            const int nxt  = cur ^ 1;

            // prefetch next step's B fragments (consumed one full step later)
            if (step + 1 < NSTEP) {
                const ushort* wnp = wc + (size_t)(step + 1) * STEP_ELEMS;
#pragma unroll
                for (int s = 0; s < 2; ++s)
#pragma unroll
                    for (int n = 0; n < 4; ++n)
                        bfr[nxt][s][n] = *(const short8*)(wnp + (((wv4 * 4 + n) * 2 + s) * 64 + lane) * 8);
            }

            // per (s,m): pack transient A-frag, feed its 4 MFMAs immediately
#pragma unroll
            for (int s = 0; s < 2; ++s)
#pragma unroll
                for (int m = 0; m < 2; ++m) {
                    union { ushort us[8]; short8 v; __hip_bfloat162 h2[4]; } pk;
#pragma unroll
                    for (int e = 0; e < 8; e += 2) {
                        pk.h2[e >> 1] = __float22bfloat162_rn(
                            make_float2(p[m][s][e], p[m][s][e + 1]));
                    }
#pragma unroll
                    for (int n = 0; n < 4; ++n)
                        acc[m][n] = __builtin_amdgcn_mfma_f32_16x16x32_bf16(
                            pk.v, bfr[cur][s][n], acc[m][n], 0, 0, 0);
                    // advance after the pack for this (m,s)
                    if (k < NK - 1)
#pragma unroll
                        for (int e = 0; e < 8; ++e) p[m][s][e] *= r[m][s][e];
                }
        }

        // chunk boundary: reload x, rebuild basis (3 times total)
        if (ic < NCHUNK - 1) {
            LOAD_X(ic + 1);
            SETUP_BASIS();
        }
    }

    // ---- epilogue: C/D layout col=lane&15, row=(lane>>4)*4+reg ----
#pragma unroll
    for (int m = 0; m < 2; ++m) {
#pragma unroll
        for (int n = 0; n < 4; ++n) {
            int col   = wv4 * 64 + n * 16 + (lane & 15);
            int rbase = rb + m * 16 + (lane >> 4) * 4;
#pragma unroll
            for (int reg = 0; reg < 4; ++reg) {
                out[(size_t)(rbase + reg) * ODIM + col] = acc[m][n][reg];
            }
        }
    }
#undef LOAD_X
#undef SETUP_BASIS
}

extern "C" void kernel_launch(void* const* d_in, const int* in_sizes, int n_in,
                              void* d_out, int out_size, void* d_ws, size_t ws_size,
                              hipStream_t stream) {
    const float* x       = (const float*)d_in[0];   // [B, I]
    const float* weights = (const float*)d_in[1];   // [O, I]
    const float* coeffs  = (const float*)d_in[2];   // [O, I, 9]
    float* out = (float*)d_out;                     // [B, O]
    ushort* wc = (ushort*)d_ws;                     // 36 * 32 KB = 1.13 MB

    prep_wc2<<<288, 256, 0, stream>>>(weights, coeffs, wc);
    bern_gemm<<<BDIM / 64, 512, 0, stream>>>(x, wc, out);
}

// Round 5
// 106.800 us; speedup vs baseline: 1.0079x; 1.0079x over previous
//
#include <hip/hip_runtime.h>
#include <hip/hip_bf16.h>

// CustomBernsteinLayer: out[b,o] = sum_{i,k} ber[b,i,k] * (coeffs[o,i,k]*weights[o,i])
// ber = (1+t)^k (1-t)^(8-k), t = tanh(x).  With e = exp2(2x*log2e):
//   (1-t) = 2/(e+1) = q, (1+t) = q*e, ratio r = e, p0 = q^8, ber_{k+1} = ber_k * r.
// bf16 MFMA GEMM M=16384 N=256 K=2304.
// Round 5: same barrier-free per-lane A-gen / register-dbuf B as R4, but the
// block is remapped to ONE 64-col slice shared by all 8 waves (waves stack in
// M). Per-block distinct B drops 1.13 MB -> 290 KB (total 580 -> 74 MB), and
// the per-step B working set (8 KB) now fits L1 with room to spare, so waves
// 1..7 hit L1 behind wave 0. B-tier bandwidth was the R1-R4 wall.

#define BDIM 16384
#define IDIM 256
#define ODIM 256
#define NK 9
#define NCHUNK 4
#define NSTEP 36
#define STEP_ELEMS (ODIM * 64)   // 16384 bf16 (32 KB) per K-step block

typedef short short8 __attribute__((ext_vector_type(8)));
typedef float floatx4 __attribute__((ext_vector_type(4)));

// ---------------------------------------------------------------------------
// prep (validated): wc[step][e] = bf16(coeffs[o,i,k]*weights[o,i]),
// e = (((o>>4)*2 + s)*64 + (o&15) + quad*16)*8 + j, il = s*32+quad*8+j,
// step = (i>>6)*9 + k. One coalesced 16B store per thread.
// ---------------------------------------------------------------------------
__global__ __launch_bounds__(256) void prep_wc2(const float* __restrict__ weights,
                                                const float* __restrict__ coeffs,
                                                ushort* __restrict__ wc) {
    int idx  = blockIdx.x * 256 + threadIdx.x;  // 73728 chunks
    int step = idx >> 11;
    int c    = idx & 2047;
    int big    = c >> 6;
    int lane_w = c & 63;
    int o    = (big >> 1) * 16 + (lane_w & 15);
    int s    = big & 1;
    int quad = lane_w >> 4;
    int ic = step / 9;
    int k  = step - ic * 9;
    int i0 = ic * 64 + s * 32 + quad * 8;

    const float* cp = coeffs + (size_t)(o * IDIM + i0) * NK + k;
    float4 w0 = *(const float4*)(weights + o * IDIM + i0);
    float4 w1 = *(const float4*)(weights + o * IDIM + i0 + 4);
    float wv[8] = {w0.x, w0.y, w0.z, w0.w, w1.x, w1.y, w1.z, w1.w};

    union { ushort us[8]; int4 v; __hip_bfloat162 h2[4]; } pk;
#pragma unroll
    for (int j = 0; j < 8; j += 2) {
        float a = cp[(size_t)j * NK] * wv[j];
        float b = cp[(size_t)(j + 1) * NK] * wv[j + 1];
        pk.h2[j >> 1] = __float22bfloat162_rn(make_float2(a, b));
    }
    *(int4*)(wc + (size_t)step * STEP_ELEMS + (size_t)c * 8) = pk.v;
}

// ---------------------------------------------------------------------------
// GEMM: 256 blocks x 512 threads (8 waves). Block = (row-group, col-group):
//   cg = blockIdx.x & 3   -> cols cg*64 .. +63 (SHARED by all 8 waves)
//   rg = blockIdx.x >> 2  -> rows rg*256; wave w -> rows rg*256 + w*32 .. +31
// Per-lane basis state for its own A-fragment slots:
//   rows rb + m*16 + (lane&15), m in {0,1}; i_local = s*32 + (lane>>4)*8 + j.
// B fragments double-buffered in registers from global; all waves load the
// SAME addresses -> L1 serves 7 of 8 waves. No LDS, no barriers.
// ---------------------------------------------------------------------------
__global__ __launch_bounds__(512, 2) void bern_gemm(const float* __restrict__ x,
                                                    const ushort* __restrict__ wc,
                                                    float* __restrict__ out) {
    const int tid  = threadIdx.x;
    const int wave = tid >> 6;
    const int lane = tid & 63;
    const int cg   = blockIdx.x & 3;
    const int rb   = (blockIdx.x >> 2) * 256 + wave * 32;
    const int lrow = lane & 15;
    const int jseg = (lane >> 4) * 8;      // 0,8,16,24

    float p[2][2][8];   // [m][s][j]: x at chunk boundary, then running ber value
    float r[2][2][8];   // ratio e = exp2(2x log2 e)
    floatx4 acc[2][4];
    floatx4 zero = {0.0f, 0.0f, 0.0f, 0.0f};
#pragma unroll
    for (int m = 0; m < 2; ++m)
#pragma unroll
        for (int n = 0; n < 4; ++n)
            acc[m][n] = zero;

    // load x for chunk ic into p[][][] (raw x values)
#define LOAD_X(ic_)                                                             \
    {                                                                           \
        _Pragma("unroll") for (int m = 0; m < 2; ++m)                           \
        _Pragma("unroll") for (int s = 0; s < 2; ++s) {                         \
            const float* xp = x + (size_t)(rb + m * 16 + lrow) * IDIM           \
                              + (ic_) * 64 + s * 32 + jseg;                     \
            float4 v0 = *(const float4*)(xp);                                   \
            float4 v1 = *(const float4*)(xp + 4);                               \
            p[m][s][0] = v0.x; p[m][s][1] = v0.y;                               \
            p[m][s][2] = v0.z; p[m][s][3] = v0.w;                               \
            p[m][s][4] = v1.x; p[m][s][5] = v1.y;                               \
            p[m][s][6] = v1.z; p[m][s][7] = v1.w;                               \
        }                                                                       \
    }

    // transform raw x in p -> (p = (1-t)^8, r = e)
#define SETUP_BASIS()                                                           \
    {                                                                           \
        _Pragma("unroll") for (int m = 0; m < 2; ++m)                           \
        _Pragma("unroll") for (int s = 0; s < 2; ++s)                           \
        _Pragma("unroll") for (int e = 0; e < 8; ++e) {                         \
            float t  = __builtin_amdgcn_exp2f(p[m][s][e] * 2.8853900817779268f);\
            float q  = 2.0f * __builtin_amdgcn_rcpf(t + 1.0f);                  \
            float q2 = q * q;                                                   \
            float q4 = q2 * q2;                                                 \
            p[m][s][e] = q4 * q4;                                               \
            r[m][s][e] = t;                                                     \
        }                                                                       \
    }

    LOAD_X(0);
    SETUP_BASIS();

    // ---- B register double-buffer; preload step 0 ----
    short8 bfr[2][2][4];   // [buf][s][n]
#pragma unroll
    for (int s = 0; s < 2; ++s)
#pragma unroll
        for (int n = 0; n < 4; ++n)
            bfr[0][s][n] = *(const short8*)(wc + (((cg * 4 + n) * 2 + s) * 64 + lane) * 8);

#pragma unroll
    for (int ic = 0; ic < NCHUNK; ++ic) {
#pragma unroll
        for (int k = 0; k < NK; ++k) {
            const int step = ic * NK + k;
            const int cur  = step & 1;
            const int nxt  = cur ^ 1;

            // prefetch next step's B fragments (consumed one full step later)
            if (step + 1 < NSTEP) {
                const ushort* wnp = wc + (size_t)(step + 1) * STEP_ELEMS;
#pragma unroll
                for (int s = 0; s < 2; ++s)
#pragma unroll
                    for (int n = 0; n < 4; ++n)
                        bfr[nxt][s][n] = *(const short8*)(wnp + (((cg * 4 + n) * 2 + s) * 64 + lane) * 8);
            }

            // per (s,m): pack transient A-frag, feed its 4 MFMAs immediately
#pragma unroll
            for (int s = 0; s < 2; ++s)
#pragma unroll
                for (int m = 0; m < 2; ++m) {
                    union { ushort us[8]; short8 v; __hip_bfloat162 h2[4]; } pk;
#pragma unroll
                    for (int e = 0; e < 8; e += 2) {
                        pk.h2[e >> 1] = __float22bfloat162_rn(
                            make_float2(p[m][s][e], p[m][s][e + 1]));
                    }
#pragma unroll
                    for (int n = 0; n < 4; ++n)
                        acc[m][n] = __builtin_amdgcn_mfma_f32_16x16x32_bf16(
                            pk.v, bfr[cur][s][n], acc[m][n], 0, 0, 0);
                    // advance after the pack for this (m,s)
                    if (k < NK - 1)
#pragma unroll
                        for (int e = 0; e < 8; ++e) p[m][s][e] *= r[m][s][e];
                }
        }

        // chunk boundary: reload x, rebuild basis (3 times total)
        if (ic < NCHUNK - 1) {
            LOAD_X(ic + 1);
            SETUP_BASIS();
        }
    }

    // ---- epilogue: C/D layout col=lane&15, row=(lane>>4)*4+reg ----
#pragma unroll
    for (int m = 0; m < 2; ++m) {
#pragma unroll
        for (int n = 0; n < 4; ++n) {
            int col   = cg * 64 + n * 16 + (lane & 15);
            int rbase = rb + m * 16 + (lane >> 4) * 4;
#pragma unroll
            for (int reg = 0; reg < 4; ++reg) {
                out[(size_t)(rbase + reg) * ODIM + col] = acc[m][n][reg];
            }
        }
    }
#undef LOAD_X
#undef SETUP_BASIS
}

extern "C" void kernel_launch(void* const* d_in, const int* in_sizes, int n_in,
                              void* d_out, int out_size, void* d_ws, size_t ws_size,
                              hipStream_t stream) {
    const float* x       = (const float*)d_in[0];   // [B, I]
    const float* weights = (const float*)d_in[1];   // [O, I]
    const float* coeffs  = (const float*)d_in[2];   // [O, I, 9]
    float* out = (float*)d_out;                     // [B, O]
    ushort* wc = (ushort*)d_ws;                     // 36 * 32 KB = 1.13 MB

    prep_wc2<<<288, 256, 0, stream>>>(weights, coeffs, wc);
    bern_gemm<<<256, 512, 0, stream>>>(x, wc, out);
}